// Round 4
// baseline (186.158 us; speedup 1.0000x reference)
//
#include <hip/hip_runtime.h>
#include <math.h>

// Problem constants (fixed shapes from setup_inputs)
#define NCLS   19
#define HW     (512*1024)          // 524288 per-image plane
#define BHW    (8*HW)              // 4194304 pixels
#define NQ     (BHW/4)             // 1048576 float4 quads
#define KSEL   262144u             // N_MIN
#define THRESH 0.35667494393873245f

struct Meta {
  double S;                 // sum of losses > THRESH
  double sumV;              // sum of losses > v (selection path)
  unsigned int cntV;        // count of losses > v
  unsigned int K;           // count of losses > THRESH
  unsigned int b1, k1, b2, k2, vbits;
  unsigned int _pad;
  unsigned int counts[32];  // label histogram
  float weights[32];        // ENet class weights
  unsigned int hist1[2048]; // radix-select level 1: bits[31:21]
  unsigned int hist2[2048]; // level 2: bits[20:10]
  unsigned int hist3[1024]; // level 3: bits[9:0]
};

// ---------------- label histogram (19 bins) ----------------
__global__ __launch_bounds__(256) void k_label_hist(const int* __restrict__ lab,
                                                    Meta* __restrict__ m) {
  __shared__ unsigned int h[32];
  if (threadIdx.x < 32) h[threadIdx.x] = 0u;
  __syncthreads();
  int q = blockIdx.x * 256 + threadIdx.x;       // grid covers NQ exactly
  int4 l = reinterpret_cast<const int4*>(lab)[q];
  atomicAdd(&h[l.x], 1u);
  atomicAdd(&h[l.y], 1u);
  atomicAdd(&h[l.z], 1u);
  atomicAdd(&h[l.w], 1u);
  __syncthreads();
  if (threadIdx.x < 32) {
    unsigned int c = h[threadIdx.x];
    if (c) atomicAdd(&m->counts[threadIdx.x], c);
  }
}

// ---------------- class weights: 1/ln(1.02 + freq) ----------------
__global__ void k_weights(Meta* __restrict__ m) {
  int c = threadIdx.x;
  if (c < NCLS) {
    float p = (float)m->counts[c] * (1.0f / (float)BHW);  // /2^22 exact
    m->weights[c] = 1.0f / logf(1.02f + p);
  }
}

// ---------------- fused weighted-CE loss + S/K accumulation ----------------
__global__ __launch_bounds__(256) void k_loss(const float* __restrict__ logits,
                                              const int* __restrict__ lab,
                                              float* __restrict__ loss,
                                              Meta* __restrict__ m) {
  __shared__ float w[NCLS];
  __shared__ float  sp[4];
  __shared__ unsigned int cp[4];
  if (threadIdx.x < NCLS) w[threadIdx.x] = m->weights[threadIdx.x];
  __syncthreads();

  int q = blockIdx.x * 256 + threadIdx.x;       // quad index, grid covers NQ
  int base = q << 2;
  int b  = base >> 19;                          // / HW (2^19)
  int hw = base & (HW - 1);
  const float* lp = logits + (long)b * (NCLS * HW) + hw;
  int4 l4 = reinterpret_cast<const int4*>(lab)[q];

  float4 vals[NCLS];
#pragma unroll
  for (int c = 0; c < NCLS; ++c) {
    vals[c] = *reinterpret_cast<const float4*>(lp);
    lp += HW;
  }

  float m0 = -INFINITY, m1 = -INFINITY, m2 = -INFINITY, m3 = -INFINITY;
#pragma unroll
  for (int c = 0; c < NCLS; ++c) {
    m0 = fmaxf(m0, vals[c].x); m1 = fmaxf(m1, vals[c].y);
    m2 = fmaxf(m2, vals[c].z); m3 = fmaxf(m3, vals[c].w);
  }
  float s0 = 0.f, s1 = 0.f, s2 = 0.f, s3 = 0.f;
  float x0 = 0.f, x1 = 0.f, x2 = 0.f, x3 = 0.f;
#pragma unroll
  for (int c = 0; c < NCLS; ++c) {
    float4 v = vals[c];
    s0 += __expf(v.x - m0); s1 += __expf(v.y - m1);
    s2 += __expf(v.z - m2); s3 += __expf(v.w - m3);
    x0 = (c == l4.x) ? v.x : x0;
    x1 = (c == l4.y) ? v.y : x1;
    x2 = (c == l4.z) ? v.z : x2;
    x3 = (c == l4.w) ? v.w : x3;
  }
  float4 o;
  o.x = w[l4.x] * (m0 + logf(s0) - x0);
  o.y = w[l4.y] * (m1 + logf(s1) - x1);
  o.z = w[l4.z] * (m2 + logf(s2) - x2);
  o.w = w[l4.w] * (m3 + logf(s3) - x3);
  reinterpret_cast<float4*>(loss)[q] = o;

  float ls = 0.f; unsigned int lc = 0u;
  if (o.x > THRESH) { ls += o.x; ++lc; }
  if (o.y > THRESH) { ls += o.y; ++lc; }
  if (o.z > THRESH) { ls += o.z; ++lc; }
  if (o.w > THRESH) { ls += o.w; ++lc; }
#pragma unroll
  for (int off = 32; off > 0; off >>= 1) {
    ls += __shfl_down(ls, off);
    lc += __shfl_down(lc, off);
  }
  int wid = threadIdx.x >> 6;
  if ((threadIdx.x & 63) == 0) { sp[wid] = ls; cp[wid] = lc; }
  __syncthreads();
  if (threadIdx.x == 0) {
    float bs = sp[0] + sp[1] + sp[2] + sp[3];
    unsigned int bc = cp[0] + cp[1] + cp[2] + cp[3];
    atomicAdd(&m->S, (double)bs);
    atomicAdd(&m->K, bc);
  }
}

// ---------------- radix select (only active when K <= N_MIN) ----------------
__global__ __launch_bounds__(256) void k_hist1(const float* __restrict__ loss,
                                               Meta* __restrict__ m) {
  __shared__ unsigned int h[2048];
  __shared__ int active;
  if (threadIdx.x == 0) active = (m->K <= KSEL) ? 1 : 0;
  for (int i = threadIdx.x; i < 2048; i += 256) h[i] = 0u;
  __syncthreads();
  if (!active) return;
  int stride = gridDim.x * 256;
  for (int q = blockIdx.x * 256 + threadIdx.x; q < NQ; q += stride) {
    float4 v = reinterpret_cast<const float4*>(loss)[q];
    atomicAdd(&h[__float_as_uint(v.x) >> 21], 1u);
    atomicAdd(&h[__float_as_uint(v.y) >> 21], 1u);
    atomicAdd(&h[__float_as_uint(v.z) >> 21], 1u);
    atomicAdd(&h[__float_as_uint(v.w) >> 21], 1u);
  }
  __syncthreads();
  for (int i = threadIdx.x; i < 2048; i += 256)
    if (h[i]) atomicAdd(&m->hist1[i], h[i]);
}

__global__ void k_sel1(Meta* __restrict__ m) {
  if (m->K > KSEL) return;
  unsigned int cum = 0;
  for (int b = 2047; b >= 0; --b) {
    unsigned int hb = m->hist1[b];
    if (cum + hb >= KSEL) { m->b1 = (unsigned)b; m->k1 = KSEL - cum; return; }
    cum += hb;
  }
}

__global__ __launch_bounds__(256) void k_hist2(const float* __restrict__ loss,
                                               Meta* __restrict__ m) {
  __shared__ unsigned int h[2048];
  __shared__ unsigned int sb1;
  __shared__ int active;
  if (threadIdx.x == 0) { active = (m->K <= KSEL) ? 1 : 0; sb1 = m->b1; }
  for (int i = threadIdx.x; i < 2048; i += 256) h[i] = 0u;
  __syncthreads();
  if (!active) return;
  unsigned int b1 = sb1;
  int stride = gridDim.x * 256;
  for (int q = blockIdx.x * 256 + threadIdx.x; q < NQ; q += stride) {
    float4 v = reinterpret_cast<const float4*>(loss)[q];
    unsigned int bx = __float_as_uint(v.x);
    unsigned int by = __float_as_uint(v.y);
    unsigned int bz = __float_as_uint(v.z);
    unsigned int bw = __float_as_uint(v.w);
    if ((bx >> 21) == b1) atomicAdd(&h[(bx >> 10) & 2047u], 1u);
    if ((by >> 21) == b1) atomicAdd(&h[(by >> 10) & 2047u], 1u);
    if ((bz >> 21) == b1) atomicAdd(&h[(bz >> 10) & 2047u], 1u);
    if ((bw >> 21) == b1) atomicAdd(&h[(bw >> 10) & 2047u], 1u);
  }
  __syncthreads();
  for (int i = threadIdx.x; i < 2048; i += 256)
    if (h[i]) atomicAdd(&m->hist2[i], h[i]);
}

__global__ void k_sel2(Meta* __restrict__ m) {
  if (m->K > KSEL) return;
  unsigned int k1 = m->k1, cum = 0;
  for (int b = 2047; b >= 0; --b) {
    unsigned int hb = m->hist2[b];
    if (cum + hb >= k1) { m->b2 = (unsigned)b; m->k2 = k1 - cum; return; }
    cum += hb;
  }
}

__global__ __launch_bounds__(256) void k_hist3(const float* __restrict__ loss,
                                               Meta* __restrict__ m) {
  __shared__ unsigned int h[1024];
  __shared__ unsigned int spre;
  __shared__ int active;
  if (threadIdx.x == 0) {
    active = (m->K <= KSEL) ? 1 : 0;
    spre = (m->b1 << 11) | m->b2;
  }
  for (int i = threadIdx.x; i < 1024; i += 256) h[i] = 0u;
  __syncthreads();
  if (!active) return;
  unsigned int pre = spre;
  int stride = gridDim.x * 256;
  for (int q = blockIdx.x * 256 + threadIdx.x; q < NQ; q += stride) {
    float4 v = reinterpret_cast<const float4*>(loss)[q];
    unsigned int bx = __float_as_uint(v.x);
    unsigned int by = __float_as_uint(v.y);
    unsigned int bz = __float_as_uint(v.z);
    unsigned int bw = __float_as_uint(v.w);
    if ((bx >> 10) == pre) atomicAdd(&h[bx & 1023u], 1u);
    if ((by >> 10) == pre) atomicAdd(&h[by & 1023u], 1u);
    if ((bz >> 10) == pre) atomicAdd(&h[bz & 1023u], 1u);
    if ((bw >> 10) == pre) atomicAdd(&h[bw & 1023u], 1u);
  }
  __syncthreads();
  for (int i = threadIdx.x; i < 1024; i += 256)
    if (h[i]) atomicAdd(&m->hist3[i], h[i]);
}

__global__ void k_sel3(Meta* __restrict__ m) {
  if (m->K > KSEL) return;
  unsigned int k2 = m->k2, cum = 0;
  for (int b = 1023; b >= 0; --b) {
    unsigned int hb = m->hist3[b];
    if (cum + hb >= k2) {
      m->vbits = (m->b1 << 21) | (m->b2 << 10) | (unsigned)b;
      return;
    }
    cum += hb;
  }
}

__global__ __launch_bounds__(256) void k_sumv(const float* __restrict__ loss,
                                              Meta* __restrict__ m) {
  __shared__ double sp[4];
  __shared__ unsigned int cp[4];
  __shared__ unsigned int svb;
  __shared__ int active;
  if (threadIdx.x == 0) { active = (m->K <= KSEL) ? 1 : 0; svb = m->vbits; }
  __syncthreads();
  if (!active) return;
  unsigned int vb = svb;
  double ls = 0.0; unsigned int lc = 0u;
  int stride = gridDim.x * 256;
  for (int q = blockIdx.x * 256 + threadIdx.x; q < NQ; q += stride) {
    float4 v = reinterpret_cast<const float4*>(loss)[q];
    if (__float_as_uint(v.x) > vb) { ls += (double)v.x; ++lc; }
    if (__float_as_uint(v.y) > vb) { ls += (double)v.y; ++lc; }
    if (__float_as_uint(v.z) > vb) { ls += (double)v.z; ++lc; }
    if (__float_as_uint(v.w) > vb) { ls += (double)v.w; ++lc; }
  }
#pragma unroll
  for (int off = 32; off > 0; off >>= 1) {
    ls += __shfl_down(ls, off);
    lc += __shfl_down(lc, off);
  }
  int wid = threadIdx.x >> 6;
  if ((threadIdx.x & 63) == 0) { sp[wid] = ls; cp[wid] = lc; }
  __syncthreads();
  if (threadIdx.x == 0) {
    atomicAdd(&m->sumV, sp[0] + sp[1] + sp[2] + sp[3]);
    atomicAdd(&m->cntV, cp[0] + cp[1] + cp[2] + cp[3]);
  }
}

// ---------------- finalize ----------------
__global__ void k_final(const Meta* __restrict__ m, float* __restrict__ out) {
  if (m->K > KSEL) {
    out[0] = (float)(m->S / (double)m->K);
  } else {
    float v = __uint_as_float(m->vbits);
    double top = m->sumV + (double)(KSEL - m->cntV) * (double)v;
    out[0] = (float)(top / (double)KSEL);
  }
}

extern "C" void kernel_launch(void* const* d_in, const int* in_sizes, int n_in,
                              void* d_out, int out_size, void* d_ws, size_t ws_size,
                              hipStream_t stream) {
  const float* logits = (const float*)d_in[0];
  const int*   labels = (const int*)d_in[1];
  float* out  = (float*)d_out;
  float* loss = (float*)d_ws;                          // 16 MiB: per-pixel losses
  Meta*  meta = (Meta*)((char*)d_ws + (size_t)BHW * 4); // metadata after loss array

  hipMemsetAsync(meta, 0, sizeof(Meta), stream);
  k_label_hist<<<NQ / 256, 256, 0, stream>>>(labels, meta);
  k_weights  <<<1, 64, 0, stream>>>(meta);
  k_loss     <<<NQ / 256, 256, 0, stream>>>(logits, labels, loss, meta);
  // OHEM fallback path (early-exits when K > N_MIN, which holds for this data)
  k_hist1    <<<512, 256, 0, stream>>>(loss, meta);
  k_sel1     <<<1, 1, 0, stream>>>(meta);
  k_hist2    <<<512, 256, 0, stream>>>(loss, meta);
  k_sel2     <<<1, 1, 0, stream>>>(meta);
  k_hist3    <<<512, 256, 0, stream>>>(loss, meta);
  k_sel3     <<<1, 1, 0, stream>>>(meta);
  k_sumv     <<<512, 256, 0, stream>>>(loss, meta);
  k_final    <<<1, 1, 0, stream>>>(meta, out);
}